// Round 5
// baseline (403.248 us; speedup 1.0000x reference)
//
#include <hip/hip_runtime.h>
#include <cstdint>
#include <cstddef>

// Match numpy/XLA float32 semantics: no FMA contraction anywhere.
#pragma clang fp contract(off)

#define KCLS 9
#define PRE_N 6000
#define POST_N 300
#define NMS_IOU_T 0.7f
#define HIST_BLOCK 256
#define CHUNKS_PER_IMG 32
#define NMS_BLOCK 512
#define NSEG 8
#define SEG_CAP 2048
#define RANK_LDS 8192   // rank_decode fast-path capacity (total candidates ~6000)

// Decisive-margin suppression test: multiply prescreen with +-1e-6 margins,
// exact reference division only in the borderline window -> bit-identical
// decisions to `inter/den > 0.7f` with reference float op order.
#define SUPP(pb, pa, mbx, mar, out) \
    bool out; { \
        float iy1_ = fmaxf((pb).x, (mbx).x); \
        float ix1_ = fmaxf((pb).y, (mbx).y); \
        float iy2_ = fminf((pb).z, (mbx).z); \
        float ix2_ = fminf((pb).w, (mbx).w); \
        float ih_ = iy2_ - iy1_; ih_ = ih_ > 0.f ? ih_ : 0.f; \
        float iw_ = ix2_ - ix1_; iw_ = iw_ > 0.f ? iw_ : 0.f; \
        float inter_ = ih_ * iw_; \
        float den_ = (mar) + (pa) - inter_ + 1e-9f; \
        float hi_ = 0.7000007f * den_; \
        float lo_ = 0.6999993f * den_; \
        out = inter_ > hi_; \
        if (inter_ >= lo_ && inter_ <= hi_) out = (inter_ / den_) > NMS_IOU_T; \
    }

// ---- inline pick: run by the LAST block of a histogram pass (256 threads) ----
// Reads the image's global histogram with agent-scope atomic loads (XCD-
// coherent), suffix-scans to locate the bin holding the krem-th largest, and
// writes {prefix,krem} to state. Identical math to the old pick_kernel.
__device__ __forceinline__ void pick_inline(
        const unsigned int* __restrict__ gh, unsigned int* __restrict__ state_img,
        int shift, int bins, int first_pass,
        unsigned int* cnt /*LDS >= bins*/, unsigned int* ssum /*LDS 256*/) {
    const int t = threadIdx.x;                  // blockDim.x == 256
    const int per = bins >> 8;                  // 8 or 4
    unsigned int my = 0;
    for (int i = 0; i < per; ++i) {
        unsigned int c = __hip_atomic_load(&gh[t * per + i],
                                           __ATOMIC_RELAXED, __HIP_MEMORY_SCOPE_AGENT);
        cnt[t * per + i] = c;
        my += c;
    }
    ssum[t] = my;
    __syncthreads();
    // inclusive suffix scan: ssum[t] = sum_{u >= t} chunk_sum[u]
    for (int d = 1; d < 256; d <<= 1) {
        unsigned int v = (t + d < 256) ? ssum[t + d] : 0u;
        __syncthreads();
        ssum[t] += v;
        __syncthreads();
    }
    unsigned int prefix = first_pass ? 0u : state_img[0];
    unsigned int krem = first_pass ? (unsigned)PRE_N : state_img[1];
    unsigned int above = ssum[t] - my;          // strictly above my chunk
    if (above < krem && ssum[t] >= krem) {      // unique thread
        unsigned int cum = above;
        for (int b = per - 1; b >= 0; --b) {
            unsigned int c = cnt[t * per + b];
            if (cum + c >= krem) {
                state_img[0] = prefix | ((unsigned int)(t * per + b) << shift);
                state_img[1] = krem - cum;
                break;
            }
            cum += c;
        }
    }
}

// ---------------- stage 1: softmax over K=9 + radix pass-1 hist + inline pick ----------------
__global__ void __launch_bounds__(256)
softmax_hist_kernel(const float* __restrict__ labels,
                    float* __restrict__ scores,
                    unsigned int* __restrict__ ghist,   // [B][2048] (pass-1 slot)
                    unsigned int* __restrict__ state,   // [B][2]
                    unsigned int* __restrict__ done,    // [B] zeroed
                    int ngroups, int bpi) {             // bpi = blocks per image (64)
    __shared__ unsigned int h[2048];
    __shared__ unsigned int ssum[256];
    __shared__ int lastblk;
    const int tid = threadIdx.x;
    for (int i = tid; i < 2048; i += 256) h[i] = 0u;
    __syncthreads();
    const int g = blockIdx.x * 256 + tid;
    if (g < ngroups) {
        const float* x = labels + (size_t)g * KCLS;
        float v[KCLS];
        float m = -1e30f;
        #pragma unroll
        for (int k = 0; k < KCLS; ++k) { v[k] = x[k]; m = fmaxf(m, v[k]); }
        float e[KCLS];
        float s = 0.f;
        #pragma unroll
        for (int k = 0; k < KCLS; ++k) { e[k] = expf(v[k] - m); s += e[k]; }
        float* o = scores + (size_t)g * KCLS;
        #pragma unroll
        for (int k = 0; k < KCLS; ++k) {
            float r = e[k] / s;
            o[k] = r;
            atomicAdd(&h[(__float_as_uint(r) >> 21) & 2047u], 1u);
        }
    }
    __syncthreads();
    const int img = blockIdx.x / bpi;            // block spans exactly one image
    unsigned int* gh = ghist + (size_t)img * 2048;
    for (int i = tid; i < 2048; i += 256) {
        unsigned int c = h[i];
        if (c) atomicAdd(&gh[i], c);
    }
    __syncthreads();                             // barrier drains vmcnt: atomics complete
    if (tid == 0) {
        __threadfence();
        unsigned int d = atomicAdd(&done[img], 1u);
        lastblk = (d == (unsigned)(bpi - 1));
    }
    __syncthreads();
    if (lastblk) {
        __threadfence();
        pick_inline(gh, state + (size_t)img * 2, 21, 2048, 1, h, ssum);
    }
}

// ---------------- stage 2a: radix histogram passes 2/3 + inline pick ----------------
__global__ void __launch_bounds__(HIST_BLOCK)
hist_pick_kernel(const float* __restrict__ scores,
                 unsigned int* __restrict__ ghist,        // [B][2048]
                 unsigned int* __restrict__ state,        // [B][2] {prefix,krem}
                 unsigned int* __restrict__ done,         // [B] zeroed
                 int A, int shift, int bins, unsigned int pmask) {
    __shared__ unsigned int h[2048];
    __shared__ unsigned int ssum[256];
    __shared__ int lastblk;
    const int img = blockIdx.y;
    const int chunk = blockIdx.x;
    const int tid = threadIdx.x;
    for (int i = tid; i < bins; i += HIST_BLOCK) h[i] = 0u;
    __syncthreads();
    unsigned int prefix = state[img * 2 + 0] & pmask;
    const int per = A / CHUNKS_PER_IMG;
    const float* sc = scores + (size_t)img * A + (size_t)chunk * per;
    for (int i = tid; i < per; i += HIST_BLOCK) {
        unsigned int v = __float_as_uint(sc[i]);   // scores > 0: uint order == float order
        if ((v & pmask) == prefix)
            atomicAdd(&h[(v >> shift) & (unsigned)(bins - 1)], 1u);
    }
    __syncthreads();
    unsigned int* gh = ghist + (size_t)img * 2048;
    for (int i = tid; i < bins; i += HIST_BLOCK) {
        unsigned int c = h[i];
        if (c) atomicAdd(&gh[i], c);
    }
    __syncthreads();                             // drains vmcnt: atomics complete
    if (tid == 0) {
        __threadfence();
        unsigned int d = atomicAdd(&done[img], 1u);
        lastblk = (d == (unsigned)(CHUNKS_PER_IMG - 1));
    }
    __syncthreads();
    if (lastblk) {
        __threadfence();
        pick_inline(gh, state + (size_t)img * 2, shift, bins, 0, h, ssum);
    }
}

// ---------------- stage 2c: per-segment compact + register-blocked bitonic sort ----------------
// grid (NSEG=8, B): block owns indices i with (i>>6)%8 == seg (round-robin
// 64-groups -> balanced: ~750 +- 26 candidates, cap 2048 = 50 sigma). Compacts
// score>=T into LDS, sorts with the register-blocked bitonic (8 elems/thread,
// NT = P2/8 active threads, double-buffered planes -> 1 barrier/stage).
#define CE(a, b, u) { if ((v[a] > v[b]) == (u)) { unsigned long long t_ = v[a]; v[a] = v[b]; v[b] = t_; } }
#define REG3(u) { CE(0,4,u) CE(1,5,u) CE(2,6,u) CE(3,7,u) \
                  CE(0,2,u) CE(1,3,u) CE(4,6,u) CE(5,7,u) \
                  CE(0,1,u) CE(2,3,u) CE(4,5,u) CE(6,7,u) }

__global__ void __launch_bounds__(512)
compact_sort_kernel(const float* __restrict__ scores,
                    const unsigned int* __restrict__ state,
                    unsigned long long* __restrict__ pool,   // [B][NSEG][SEG_CAP]
                    unsigned int* __restrict__ counts,       // [B][NSEG]
                    int A) {
    __shared__ unsigned long long lin[SEG_CAP];   // 16 KB
    __shared__ unsigned int plo[2][SEG_CAP];      // 16 KB
    __shared__ unsigned int phi[2][SEG_CAP];      // 16 KB
    __shared__ unsigned int cnt;
    const int img = blockIdx.y;
    const int seg = blockIdx.x;
    const int tid = threadIdx.x;
    const int lane = tid & 63;
    const int w = tid >> 6;                       // wave 0..7
    const float* sc = scores + (size_t)img * A;
    const unsigned int T = state[img * 2 + 0];    // exact bits of 6000th-largest score

    if (tid == 0) cnt = 0u;
    for (int i = tid; i < SEG_CAP; i += 512) lin[i] = ~0ull;  // pad keys = max
    __syncthreads();

    // compact: groups g == seg (mod NSEG), wave-aggregated LDS push
    const int ngr = A >> 6;                       // 64-element groups (2304)
    const int nj = ngr / NSEG;                    // groups per segment (288)
    for (int j = w; j < nj; j += 8) {             // 36 iterations per wave
        int g = seg + j * NSEG;
        int i = (g << 6) + lane;
        unsigned int sv = __float_as_uint(sc[i]); // scores > 0: uint order == float order
        bool push = (sv >= T);
        unsigned long long bal = __ballot(push ? 1 : 0);
        if (push) {
            int leader = __ffsll(bal) - 1;
            int rank = __popcll(bal & ((1ull << lane) - 1ull));
            unsigned int base = 0;
            if (lane == leader) base = atomicAdd(&cnt, (unsigned int)__popcll(bal));
            base = (unsigned int)__shfl((int)base, leader);
            unsigned int pos = base + (unsigned int)rank;
            if (pos < SEG_CAP)
                lin[pos] = (((unsigned long long)(~sv)) << 32) | (unsigned long long)(unsigned int)i;
        }
    }
    __syncthreads();

    int n = (int)cnt; if (n > SEG_CAP) n = SEG_CAP;
    int P2 = 512; while (P2 < n) P2 <<= 1;        // 512..2048 (block-uniform)
    const int NT = P2 >> 3;                       // active threads
    const int t = tid;
    const bool act = (t < NT);

    unsigned long long v[8];
    if (act) {
        #pragma unroll
        for (int e = 0; e < 8; ++e) v[e] = lin[(t << 3) + e];
        // k=2,4,8 (in-register)
        CE(0,1,true) CE(2,3,false) CE(4,5,true) CE(6,7,false)
        CE(0,2,true) CE(1,3,true) CE(4,6,false) CE(5,7,false)
        CE(0,1,true) CE(2,3,true) CE(4,5,false) CE(6,7,false)
        bool u8 = ((t & 1) == 0);
        REG3(u8)
    }
    int b = 0;
    for (int k = 16; k <= P2; k <<= 1) {
        const bool up = (((t << 3) & k) == 0);
        for (int j = k >> 1; j >= 8; j >>= 1) {
            const int c = j >> 3;
            if (act) {
                #pragma unroll
                for (int e = 0; e < 8; ++e) {
                    int idx = e * NT + t;
                    plo[b][idx] = (unsigned int)v[e];
                    phi[b][idx] = (unsigned int)(v[e] >> 32);
                }
            }
            __syncthreads();
            if (act) {
                const int q = t ^ c;
                const bool keep_min = (up == ((t & c) == 0));
                #pragma unroll
                for (int e = 0; e < 8; ++e) {
                    int idx = e * NT + q;
                    unsigned long long wv = ((unsigned long long)phi[b][idx] << 32)
                                          | (unsigned long long)plo[b][idx];
                    bool less = v[e] < wv;
                    v[e] = (less == keep_min) ? v[e] : wv;
                }
            }
            b ^= 1;
        }
        if (act) { REG3(up) }
    }

    unsigned long long* gp = pool + ((size_t)img * NSEG + seg) * SEG_CAP;
    if (act) {
        #pragma unroll
        for (int e = 0; e < 8; ++e) {
            int r = (t << 3) + e;
            if (r < n) gp[r] = v[e];
        }
    }
    if (tid == 0) counts[img * NSEG + seg] = (unsigned int)n;
}

// ---------------- stage 2d: rank (merge by binary search) + decode ----------------
__global__ void __launch_bounds__(256)
rank_decode_kernel(const unsigned long long* __restrict__ pool,
                   const unsigned int* __restrict__ counts,
                   const float* __restrict__ deltas,   // [B][A][4]
                   const float* __restrict__ anchors,  // [A][4]
                   float* __restrict__ pre_boxes,      // [B][6000][4]
                   float* __restrict__ pre_scores,     // [B][6000]
                   int A) {
    __shared__ unsigned long long arr[RANK_LDS];   // 64 KB (total ~6000 -> fast path)
    const int img = blockIdx.y;
    const int seg = blockIdx.x;
    const int tid = threadIdx.x;

    int c[NSEG], off[NSEG + 1];
    const unsigned long long* gp[NSEG];
    off[0] = 0;
    #pragma unroll
    for (int s = 0; s < NSEG; ++s) {
        int cs = (int)counts[img * NSEG + s];
        if (cs > SEG_CAP) cs = SEG_CAP;
        c[s] = cs;
        off[s + 1] = off[s] + cs;
        gp[s] = pool + ((size_t)img * NSEG + s) * SEG_CAP;
    }
    const int total = off[NSEG];
    const bool inlds = (total <= RANK_LDS);
    if (inlds) {
        #pragma unroll
        for (int s = 0; s < NSEG; ++s)
            for (int i = tid; i < c[s]; i += 256) arr[off[s] + i] = gp[s][i];
    }
    __syncthreads();

    const int m = c[seg];
    for (int i = tid; i < m; i += 256) {
        unsigned long long key = inlds ? arr[off[seg] + i] : gp[seg][i];
        int pos = i;
        #pragma unroll
        for (int s = 0; s < NSEG; ++s) {
            if (s == seg) continue;
            const unsigned long long* base = inlds ? (arr + off[s]) : gp[s];
            int lo = 0, hi = c[s];
            while (lo < hi) {
                int mid = (lo + hi) >> 1;
                if (base[mid] < key) lo = mid + 1; else hi = mid;
            }
            pos += lo;
        }
        if (pos < PRE_N) {
            unsigned int bidx = (unsigned int)(key & 0xFFFFFFFFull);
            unsigned int sbits = ~((unsigned int)(key >> 32));
            float score = __uint_as_float(sbits);
            float a0 = anchors[(size_t)bidx * 4 + 0];
            float a1 = anchors[(size_t)bidx * 4 + 1];
            float a2 = anchors[(size_t)bidx * 4 + 2];
            float a3 = anchors[(size_t)bidx * 4 + 3];
            const float* dd = deltas + ((size_t)img * A + bidx) * 4;
            float d0 = dd[0] * 0.1f;
            float d1 = dd[1] * 0.1f;
            float d2 = dd[2] * 0.2f;
            float d3 = dd[3] * 0.2f;
            float anc_w = a3 - a1;
            float anc_h = a2 - a0;
            float anc_cx = a1 + 0.5f * anc_w;
            float anc_cy = a0 + 0.5f * anc_h;
            float bb_w = expf(d3) * anc_w;
            float bb_h = expf(d2) * anc_h;
            float bb_cx = d1 * anc_w + anc_cx;
            float bb_cy = d0 * anc_h + anc_cy;
            float y1 = bb_cy - 0.5f * bb_h;
            float x1 = bb_cx - 0.5f * bb_w;
            float y2 = bb_h + y1;
            float x2 = bb_w + x1;
            float* ob = pre_boxes + ((size_t)img * PRE_N + pos) * 4;
            ob[0] = y1; ob[1] = x1; ob[2] = y2; ob[3] = x2;
            pre_scores[(size_t)img * PRE_N + pos] = score;
        }
    }
}

// ---------------- stage 3: chunked greedy NMS (suppression-matrix resolution) ----------------
__global__ void __launch_bounds__(NMS_BLOCK)
nms_kernel(const float* __restrict__ pre_boxes,
           const float* __restrict__ pre_scores,
           float* __restrict__ out_boxes,    // [B][300][4] (pre-zeroed)
           float* __restrict__ out_scores) { // [B][300]
    const int img = blockIdx.x;
    const int tid = threadIdx.x;
    const int lane = tid & 63;
    const int grp = tid >> 6;                 // 0..7
    const float4* bb4 = (const float4*)(pre_boxes + (size_t)img * PRE_N * 4);

    __shared__ float4 kept[POST_N];           // kept boxes (in keep order)
    __shared__ float  kept_area[POST_N];
    __shared__ int    kept_idx[POST_N];       // global index into pre_* arrays
    __shared__ float4 chunkbox[64];
    __shared__ unsigned long long part[8][64];  // per-wave partial column masks
    __shared__ unsigned long long supcol[64];   // full column masks
    __shared__ unsigned long long chunk_alive;  // ext-alive (phase E survivors)
    __shared__ int kept_cnt;

    if (tid == 0) kept_cnt = 0;

    const int NCH = (PRE_N + 63) >> 6;        // 94 (last chunk: 48 valid)

    // prefetch chunk 0 (grp 0 owns staging)
    float4 nb = make_float4(0.f, 0.f, 0.f, 0.f);
    if (grp == 0) nb = bb4[lane];             // chunk 0 fully valid (64 <= 6000)

    for (int c = 0; c < NCH; ++c) {
        const int base = c << 6;
        if (grp == 0) chunkbox[lane] = nb;
        if (tid == 0) {
            int rem = PRE_N - base;
            chunk_alive = (rem >= 64) ? ~0ull : ((1ull << rem) - 1ull);
        }
        __syncthreads();                      // (A) chunkbox + alive-init visible

        // issue next-chunk prefetch early; latency hides under phases E/M
        if (grp == 0 && c + 1 < NCH) {
            int j = base + 64 + lane;
            nb = (j < PRE_N) ? bb4[j] : make_float4(0.f, 0.f, 0.f, 0.f);
        }

        const int K = kept_cnt;
        float4 mb = chunkbox[lane];
        float marea = (mb.z - mb.x) * (mb.w - mb.y);

        // ---- phase E: external suppression vs previously-kept boxes ----
        bool sup = false;
        for (int k = grp; k < K; k += 8) {
            float4 pb = kept[k];              // LDS broadcast (uniform addr per wave)
            float pa = kept_area[k];
            SUPP(pb, pa, mb, marea, s)
            if (s) { sup = true; break; }
        }
        unsigned long long bal = __ballot(sup ? 1 : 0);
        if (lane == 0 && bal) atomicAnd(&chunk_alive, ~bal);

        // ---- phase M: within-chunk suppression matrix (8 pivots per wave) ----
        unsigned long long pm = 0ull;
        #pragma unroll
        for (int u = 0; u < 8; ++u) {
            const int i = (grp << 3) + u;
            float4 pb = chunkbox[i];          // uniform per iteration -> broadcast
            float pa = (pb.z - pb.x) * (pb.w - pb.y);
            SUPP(pb, pa, mb, marea, s)
            if (s) pm |= (1ull << i);
        }
        part[grp][lane] = pm;
        __syncthreads();                      // (B) chunk_alive + partials final

        // ---- phase R: wave-0 bitmask resolution ----
        if (grp == 0) {
            unsigned long long col = part[0][lane] | part[1][lane] | part[2][lane] | part[3][lane]
                                   | part[4][lane] | part[5][lane] | part[6][lane] | part[7][lane];
            supcol[lane] = col;               // same-wave write->read: LDS ops in order
            const unsigned long long extm = chunk_alive;
            unsigned long long aliveset = 0ull;
            int kc = K;
            #pragma unroll 8
            for (int i = 0; i < 64; ++i) {
                unsigned long long mi = supcol[i];   // uniform loads hoist out of chain
                bool keep = (((extm >> i) & 1ull) != 0ull) &&
                            ((mi & aliveset) == 0ull) && (kc < POST_N);
                if (keep) {                   // wave-uniform branch
                    if (lane == i) {
                        kept[kc] = mb;
                        kept_area[kc] = marea;
                        kept_idx[kc] = base + i;
                    }
                    aliveset |= (1ull << i);
                    ++kc;
                }
            }
            if (lane == 0) kept_cnt = kc;
        }
        __syncthreads();                      // (C) kept list + count visible
        if (kept_cnt >= POST_N) break;        // uniform
    }

    // ---- write outputs (rest of the pre-zeroed buffer stays zero) ----
    const int kc = kept_cnt;
    for (int r = tid; r < kc; r += NMS_BLOCK) {
        float4 bx = kept[r];
        float* ob = out_boxes + ((size_t)img * POST_N + r) * 4;
        ob[0] = bx.x; ob[1] = bx.y; ob[2] = bx.z; ob[3] = bx.w;
        out_scores[(size_t)img * POST_N + r] =
            pre_scores[(size_t)img * PRE_N + kept_idx[r]];
    }
}

extern "C" void kernel_launch(void* const* d_in, const int* in_sizes, int n_in,
                              void* d_out, int out_size, void* d_ws, size_t ws_size,
                              hipStream_t stream) {
    const float* deltas  = (const float*)d_in[0];  // (B, A, 4)
    const float* labels  = (const float*)d_in[1];  // (B, FH, FW, 9)
    const float* anchors = (const float*)d_in[2];  // (A, 4)
    float* out = (float*)d_out;

    const int A = in_sizes[2] / 4;                 // 147456
    const int B = in_sizes[0] / (A * 4);           // 32
    const int ngroups = in_sizes[1] / KCLS;        // B*FH*FW
    const int gpi = ngroups / B;                   // 16384
    const int bpi = gpi / 256;                     // softmax blocks per image (64)

    // workspace layout
    float* scores     = (float*)d_ws;                                // B*A
    float* pre_boxes  = scores + (size_t)B * A;                      // B*6000*4
    float* pre_scores = pre_boxes + (size_t)B * PRE_N * 4;           // B*6000
    unsigned int* hist  = (unsigned int*)(pre_scores + (size_t)B * PRE_N);  // 3*B*2048
    unsigned int* done  = hist + (size_t)3 * B * 2048;               // 3*B
    unsigned int* state = done + (size_t)3 * B;                      // B*2
    unsigned long long* pool = (unsigned long long*)(state + (size_t)B * 2); // B*NSEG*SEG_CAP u64
    unsigned int* counts = (unsigned int*)(pool + (size_t)B * NSEG * SEG_CAP); // B*NSEG

    float* out_boxes  = out;                        // B*300*4
    float* out_scores = out + (size_t)B * POST_N * 4;

    hipMemsetAsync(d_out, 0, (size_t)out_size * sizeof(float), stream);
    hipMemsetAsync(hist, 0, ((size_t)3 * B * 2048 + 3 * B + 2 * B) * sizeof(unsigned int), stream);

    // pass 1 (bits [31:21]) fused into softmax; pick runs in the last-done block
    softmax_hist_kernel<<<(ngroups + 255) / 256, 256, 0, stream>>>(
        labels, scores, hist + (size_t)0 * B * 2048, state, done + 0 * B, ngroups, bpi);

    dim3 hgrid(CHUNKS_PER_IMG, B);
    // pass 2: bits [20:10]
    hist_pick_kernel<<<hgrid, HIST_BLOCK, 0, stream>>>(
        scores, hist + (size_t)1 * B * 2048, state, done + 1 * B, A, 10, 2048, 0xFFE00000u);
    // pass 3: bits [9:0]
    hist_pick_kernel<<<hgrid, HIST_BLOCK, 0, stream>>>(
        scores, hist + (size_t)2 * B * 2048, state, done + 2 * B, A, 0, 1024, 0xFFFFFC00u);

    dim3 sgrid(NSEG, B);
    compact_sort_kernel<<<sgrid, 512, 0, stream>>>(scores, state, pool, counts, A);
    rank_decode_kernel<<<sgrid, 256, 0, stream>>>(pool, counts, deltas, anchors,
                                                  pre_boxes, pre_scores, A);

    nms_kernel<<<B, NMS_BLOCK, 0, stream>>>(pre_boxes, pre_scores, out_boxes, out_scores);
}

// Round 6
// 260.940 us; speedup vs baseline: 1.5454x; 1.5454x over previous
//
#include <hip/hip_runtime.h>
#include <cstdint>
#include <cstddef>

// Match numpy/XLA float32 semantics: no FMA contraction anywhere.
#pragma clang fp contract(off)

#define KCLS 9
#define PRE_N 6000
#define POST_N 300
#define NMS_IOU_T 0.7f
#define HIST_BLOCK 256
#define CHUNKS_PER_IMG 32
#define NMS_BLOCK 512
#define PICK_BLOCK 256
#define NSEG 8
#define SEG_CAP 2048
#define RANK_LDS 8192   // rank_decode fast-path capacity (total candidates ~6000+eps)

// Decisive-margin suppression test: multiply prescreen with +-1e-6 margins,
// exact reference division only in the borderline window -> bit-identical
// decisions to `inter/den > 0.7f` with reference float op order.
#define SUPP(pb, pa, mbx, mar, out) \
    bool out; { \
        float iy1_ = fmaxf((pb).x, (mbx).x); \
        float ix1_ = fmaxf((pb).y, (mbx).y); \
        float iy2_ = fminf((pb).z, (mbx).z); \
        float ix2_ = fminf((pb).w, (mbx).w); \
        float ih_ = iy2_ - iy1_; ih_ = ih_ > 0.f ? ih_ : 0.f; \
        float iw_ = ix2_ - ix1_; iw_ = iw_ > 0.f ? iw_ : 0.f; \
        float inter_ = ih_ * iw_; \
        float den_ = (mar) + (pa) - inter_ + 1e-9f; \
        float hi_ = 0.7000007f * den_; \
        float lo_ = 0.6999993f * den_; \
        out = inter_ > hi_; \
        if (inter_ >= lo_ && inter_ <= hi_) out = (inter_ / den_) > NMS_IOU_T; \
    }

// ---------------- stage 1: softmax over K=9 (LDS-staged coalesced IO) + pass-1 hist ----------------
// ngroups % 256 == 0 (B*FH*FW = 524288), so every block handles exactly 256
// groups = 2304 floats = 576 float4, 16B-aligned (2304*4 % 16 == 0).
__global__ void __launch_bounds__(256)
softmax_hist_kernel(const float* __restrict__ labels,
                    float* __restrict__ scores,
                    unsigned int* __restrict__ ghist,   // [B][2048] (pass-1 slot)
                    int gpi) {                          // groups per image (16384)
    __shared__ float buf[256 * KCLS];                   // 9216 B
    __shared__ unsigned int h[2048];                    // 8192 B
    const int tid = threadIdx.x;
    for (int i = tid; i < 2048; i += 256) h[i] = 0u;

    const size_t gbase = (size_t)blockIdx.x * (256 * KCLS);
    const float4* lin4 = (const float4*)(labels + gbase);
    float4* b4 = (float4*)buf;
    for (int i = tid; i < 576; i += 256) b4[i] = lin4[i];   // coalesced 16B loads
    __syncthreads();

    // per-thread softmax on buf[tid*9 .. +8]; stride-9 LDS = 2-way aliasing (free)
    float v[KCLS];
    float m = -1e30f;
    #pragma unroll
    for (int k = 0; k < KCLS; ++k) { v[k] = buf[tid * KCLS + k]; m = fmaxf(m, v[k]); }
    float e[KCLS];
    float s = 0.f;
    #pragma unroll
    for (int k = 0; k < KCLS; ++k) { e[k] = expf(v[k] - m); s += e[k]; }
    #pragma unroll
    for (int k = 0; k < KCLS; ++k) {
        float r = e[k] / s;
        buf[tid * KCLS + k] = r;                        // own slots only: no hazard
        atomicAdd(&h[(__float_as_uint(r) >> 21) & 2047u], 1u);
    }
    __syncthreads();

    float4* o4 = (float4*)(scores + gbase);
    for (int i = tid; i < 576; i += 256) o4[i] = b4[i];     // coalesced 16B stores

    const int img0 = (blockIdx.x * 256) / gpi;          // block spans one image
    unsigned int* gh = ghist + (size_t)img0 * 2048;
    for (int i = tid; i < 2048; i += 256) {
        unsigned int c = h[i];
        if (c) atomicAdd(&gh[i], c);
    }
}

// ---------------- stage 2a: radix histogram pass 2 ----------------
__global__ void hist_kernel(const float* __restrict__ scores,
                            unsigned int* __restrict__ ghist,        // [B][2048]
                            const unsigned int* __restrict__ state,  // [B][2] {prefix,krem}
                            int A, int shift, int bins, unsigned int pmask) {
    __shared__ unsigned int h[2048];
    const int img = blockIdx.y;
    const int chunk = blockIdx.x;
    const int tid = threadIdx.x;
    for (int i = tid; i < bins; i += HIST_BLOCK) h[i] = 0u;
    __syncthreads();
    unsigned int prefix = state[img * 2 + 0] & pmask;
    const int per = A / CHUNKS_PER_IMG;
    const float* sc = scores + (size_t)img * A + (size_t)chunk * per;
    for (int i = tid; i < per; i += HIST_BLOCK) {
        unsigned int v = __float_as_uint(sc[i]);   // scores > 0: uint order == float order
        if ((v & pmask) == prefix)
            atomicAdd(&h[(v >> shift) & (unsigned)(bins - 1)], 1u);
    }
    __syncthreads();
    unsigned int* gh = ghist + (size_t)img * 2048;
    for (int i = tid; i < bins; i += HIST_BLOCK) {
        unsigned int c = h[i];
        if (c) atomicAdd(&gh[i], c);
    }
}

// ---------------- stage 2b: pick target bin (parallel suffix scan) ----------------
__global__ void __launch_bounds__(PICK_BLOCK)
pick_kernel(const unsigned int* __restrict__ ghist,
            unsigned int* __restrict__ state,
            int shift, int bins, int first_pass) {
    const int img = blockIdx.x;
    const int t = threadIdx.x;
    const unsigned int* gh = ghist + (size_t)img * 2048;
    __shared__ unsigned int cnt[2048];
    __shared__ unsigned int ssum[PICK_BLOCK];
    const int per = bins / PICK_BLOCK;   // 8
    unsigned int my = 0;
    for (int i = 0; i < per; ++i) {
        unsigned int c = gh[t * per + i];
        cnt[t * per + i] = c;
        my += c;
    }
    ssum[t] = my;
    __syncthreads();
    // inclusive suffix scan: ssum[t] = sum_{u >= t} chunk_sum[u]
    for (int d = 1; d < PICK_BLOCK; d <<= 1) {
        unsigned int v = (t + d < PICK_BLOCK) ? ssum[t + d] : 0u;
        __syncthreads();
        ssum[t] += v;
        __syncthreads();
    }
    unsigned int prefix = first_pass ? 0u : state[img * 2 + 0];
    unsigned int krem = first_pass ? (unsigned)PRE_N : state[img * 2 + 1];
    unsigned int above = ssum[t] - my;   // strictly above my chunk
    if (above < krem && ssum[t] >= krem) {   // unique thread
        unsigned int cum = above;
        for (int b = per - 1; b >= 0; --b) {
            unsigned int c = cnt[t * per + b];
            if (cum + c >= krem) {
                state[img * 2 + 0] = prefix | ((unsigned int)(t * per + b) << shift);
                state[img * 2 + 1] = krem - cum;
                break;
            }
            cum += c;
        }
    }
}

// ---------------- stage 2c: per-segment compact + register-blocked bitonic sort ----------------
// T = state[0] after TWO radix passes = top-22 bits of the 6000th-largest score
// (low 10 bits zero). Loose-but-safe threshold: candidates = 6000 + (elements
// sharing the 22-bit prefix below the exact cut) ~ 6000+dozens. The exact top-
// 6000 cut happens later on full 64-bit keys in rank_decode -> output identical.
#define CE(a, b, u) { if ((v[a] > v[b]) == (u)) { unsigned long long t_ = v[a]; v[a] = v[b]; v[b] = t_; } }
#define REG3(u) { CE(0,4,u) CE(1,5,u) CE(2,6,u) CE(3,7,u) \
                  CE(0,2,u) CE(1,3,u) CE(4,6,u) CE(5,7,u) \
                  CE(0,1,u) CE(2,3,u) CE(4,5,u) CE(6,7,u) }

__global__ void __launch_bounds__(512)
compact_sort_kernel(const float* __restrict__ scores,
                    const unsigned int* __restrict__ state,
                    unsigned long long* __restrict__ pool,   // [B][NSEG][SEG_CAP]
                    unsigned int* __restrict__ counts,       // [B][NSEG]
                    int A) {
    __shared__ unsigned long long lin[SEG_CAP];   // 16 KB
    __shared__ unsigned int plo[2][SEG_CAP];      // 16 KB
    __shared__ unsigned int phi[2][SEG_CAP];      // 16 KB
    __shared__ unsigned int cnt;
    const int img = blockIdx.y;
    const int seg = blockIdx.x;
    const int tid = threadIdx.x;
    const int lane = tid & 63;
    const int w = tid >> 6;                       // wave 0..7
    const float* sc = scores + (size_t)img * A;
    const unsigned int T = state[img * 2 + 0];    // 22-bit-prefix threshold

    if (tid == 0) cnt = 0u;
    for (int i = tid; i < SEG_CAP; i += 512) lin[i] = ~0ull;  // pad keys = max
    __syncthreads();

    // compact: groups g == seg (mod NSEG), wave-aggregated LDS push
    const int ngr = A >> 6;                       // 64-element groups (2304)
    const int nj = ngr / NSEG;                    // groups per segment (288)
    for (int j = w; j < nj; j += 8) {             // 36 iterations per wave
        int g = seg + j * NSEG;
        int i = (g << 6) + lane;
        unsigned int sv = __float_as_uint(sc[i]); // scores > 0: uint order == float order
        bool push = (sv >= T);
        unsigned long long bal = __ballot(push ? 1 : 0);
        if (push) {
            int leader = __ffsll(bal) - 1;
            int rank = __popcll(bal & ((1ull << lane) - 1ull));
            unsigned int base = 0;
            if (lane == leader) base = atomicAdd(&cnt, (unsigned int)__popcll(bal));
            base = (unsigned int)__shfl((int)base, leader);
            unsigned int pos = base + (unsigned int)rank;
            if (pos < SEG_CAP)
                lin[pos] = (((unsigned long long)(~sv)) << 32) | (unsigned long long)(unsigned int)i;
        }
    }
    __syncthreads();

    int n = (int)cnt; if (n > SEG_CAP) n = SEG_CAP;
    int P2 = 512; while (P2 < n) P2 <<= 1;        // 512..2048 (block-uniform)
    const int NT = P2 >> 3;                       // active threads
    const int t = tid;
    const bool act = (t < NT);

    unsigned long long v[8];
    if (act) {
        #pragma unroll
        for (int e = 0; e < 8; ++e) v[e] = lin[(t << 3) + e];
        // k=2,4,8 (in-register)
        CE(0,1,true) CE(2,3,false) CE(4,5,true) CE(6,7,false)
        CE(0,2,true) CE(1,3,true) CE(4,6,false) CE(5,7,false)
        CE(0,1,true) CE(2,3,true) CE(4,5,false) CE(6,7,false)
        bool u8 = ((t & 1) == 0);
        REG3(u8)
    }
    int b = 0;
    for (int k = 16; k <= P2; k <<= 1) {
        const bool up = (((t << 3) & k) == 0);
        for (int j = k >> 1; j >= 8; j >>= 1) {
            const int c = j >> 3;
            if (act) {
                #pragma unroll
                for (int e = 0; e < 8; ++e) {
                    int idx = e * NT + t;
                    plo[b][idx] = (unsigned int)v[e];
                    phi[b][idx] = (unsigned int)(v[e] >> 32);
                }
            }
            __syncthreads();
            if (act) {
                const int q = t ^ c;
                const bool keep_min = (up == ((t & c) == 0));
                #pragma unroll
                for (int e = 0; e < 8; ++e) {
                    int idx = e * NT + q;
                    unsigned long long wv = ((unsigned long long)phi[b][idx] << 32)
                                          | (unsigned long long)plo[b][idx];
                    bool less = v[e] < wv;
                    v[e] = (less == keep_min) ? v[e] : wv;
                }
            }
            b ^= 1;
        }
        if (act) { REG3(up) }
    }

    unsigned long long* gp = pool + ((size_t)img * NSEG + seg) * SEG_CAP;
    if (act) {
        #pragma unroll
        for (int e = 0; e < 8; ++e) {
            int r = (t << 3) + e;
            if (r < n) gp[r] = v[e];
        }
    }
    if (tid == 0) counts[img * NSEG + seg] = (unsigned int)n;
}

// ---------------- stage 2d: rank (merge by binary search) + decode ----------------
__global__ void __launch_bounds__(256)
rank_decode_kernel(const unsigned long long* __restrict__ pool,
                   const unsigned int* __restrict__ counts,
                   const float* __restrict__ deltas,   // [B][A][4]
                   const float* __restrict__ anchors,  // [A][4]
                   float* __restrict__ pre_boxes,      // [B][6000][4]
                   float* __restrict__ pre_scores,     // [B][6000]
                   int A) {
    __shared__ unsigned long long arr[RANK_LDS];   // 64 KB (total ~6000 -> fast path)
    const int img = blockIdx.y;
    const int seg = blockIdx.x;
    const int tid = threadIdx.x;

    int c[NSEG], off[NSEG + 1];
    const unsigned long long* gp[NSEG];
    off[0] = 0;
    #pragma unroll
    for (int s = 0; s < NSEG; ++s) {
        int cs = (int)counts[img * NSEG + s];
        if (cs > SEG_CAP) cs = SEG_CAP;
        c[s] = cs;
        off[s + 1] = off[s] + cs;
        gp[s] = pool + ((size_t)img * NSEG + s) * SEG_CAP;
    }
    const int total = off[NSEG];
    const bool inlds = (total <= RANK_LDS);
    if (inlds) {
        #pragma unroll
        for (int s = 0; s < NSEG; ++s)
            for (int i = tid; i < c[s]; i += 256) arr[off[s] + i] = gp[s][i];
    }
    __syncthreads();

    const int m = c[seg];
    for (int i = tid; i < m; i += 256) {
        unsigned long long key = inlds ? arr[off[seg] + i] : gp[seg][i];
        int pos = i;
        #pragma unroll
        for (int s = 0; s < NSEG; ++s) {
            if (s == seg) continue;
            const unsigned long long* base = inlds ? (arr + off[s]) : gp[s];
            int lo = 0, hi = c[s];
            while (lo < hi) {
                int mid = (lo + hi) >> 1;
                if (base[mid] < key) lo = mid + 1; else hi = mid;
            }
            pos += lo;
        }
        if (pos < PRE_N) {
            unsigned int bidx = (unsigned int)(key & 0xFFFFFFFFull);
            unsigned int sbits = ~((unsigned int)(key >> 32));
            float score = __uint_as_float(sbits);
            float a0 = anchors[(size_t)bidx * 4 + 0];
            float a1 = anchors[(size_t)bidx * 4 + 1];
            float a2 = anchors[(size_t)bidx * 4 + 2];
            float a3 = anchors[(size_t)bidx * 4 + 3];
            const float* dd = deltas + ((size_t)img * A + bidx) * 4;
            float d0 = dd[0] * 0.1f;
            float d1 = dd[1] * 0.1f;
            float d2 = dd[2] * 0.2f;
            float d3 = dd[3] * 0.2f;
            float anc_w = a3 - a1;
            float anc_h = a2 - a0;
            float anc_cx = a1 + 0.5f * anc_w;
            float anc_cy = a0 + 0.5f * anc_h;
            float bb_w = expf(d3) * anc_w;
            float bb_h = expf(d2) * anc_h;
            float bb_cx = d1 * anc_w + anc_cx;
            float bb_cy = d0 * anc_h + anc_cy;
            float y1 = bb_cy - 0.5f * bb_h;
            float x1 = bb_cx - 0.5f * bb_w;
            float y2 = bb_h + y1;
            float x2 = bb_w + x1;
            float* ob = pre_boxes + ((size_t)img * PRE_N + pos) * 4;
            ob[0] = y1; ob[1] = x1; ob[2] = y2; ob[3] = x2;
            pre_scores[(size_t)img * PRE_N + pos] = score;
        }
    }
}

// ---------------- stage 3: chunked greedy NMS (suppression-matrix resolution) ----------------
__global__ void __launch_bounds__(NMS_BLOCK)
nms_kernel(const float* __restrict__ pre_boxes,
           const float* __restrict__ pre_scores,
           float* __restrict__ out_boxes,    // [B][300][4] (pre-zeroed)
           float* __restrict__ out_scores) { // [B][300]
    const int img = blockIdx.x;
    const int tid = threadIdx.x;
    const int lane = tid & 63;
    const int grp = tid >> 6;                 // 0..7
    const float4* bb4 = (const float4*)(pre_boxes + (size_t)img * PRE_N * 4);

    __shared__ float4 kept[POST_N];           // kept boxes (in keep order)
    __shared__ float  kept_area[POST_N];
    __shared__ int    kept_idx[POST_N];       // global index into pre_* arrays
    __shared__ float4 chunkbox[64];
    __shared__ unsigned long long part[8][64];  // per-wave partial column masks
    __shared__ unsigned long long supcol[64];   // full column masks
    __shared__ unsigned long long chunk_alive;  // ext-alive (phase E survivors)
    __shared__ int kept_cnt;

    if (tid == 0) kept_cnt = 0;

    const int NCH = (PRE_N + 63) >> 6;        // 94 (last chunk: 48 valid)

    // prefetch chunk 0 (grp 0 owns staging)
    float4 nb = make_float4(0.f, 0.f, 0.f, 0.f);
    if (grp == 0) nb = bb4[lane];             // chunk 0 fully valid (64 <= 6000)

    for (int c = 0; c < NCH; ++c) {
        const int base = c << 6;
        if (grp == 0) chunkbox[lane] = nb;
        if (tid == 0) {
            int rem = PRE_N - base;
            chunk_alive = (rem >= 64) ? ~0ull : ((1ull << rem) - 1ull);
        }
        __syncthreads();                      // (A) chunkbox + alive-init visible

        // issue next-chunk prefetch early; latency hides under phases E/M
        if (grp == 0 && c + 1 < NCH) {
            int j = base + 64 + lane;
            nb = (j < PRE_N) ? bb4[j] : make_float4(0.f, 0.f, 0.f, 0.f);
        }

        const int K = kept_cnt;
        float4 mb = chunkbox[lane];
        float marea = (mb.z - mb.x) * (mb.w - mb.y);

        // ---- phase E: external suppression vs previously-kept boxes ----
        bool sup = false;
        for (int k = grp; k < K; k += 8) {
            float4 pb = kept[k];              // LDS broadcast (uniform addr per wave)
            float pa = kept_area[k];
            SUPP(pb, pa, mb, marea, s)
            if (s) { sup = true; break; }
        }
        unsigned long long bal = __ballot(sup ? 1 : 0);
        if (lane == 0 && bal) atomicAnd(&chunk_alive, ~bal);

        // ---- phase M: within-chunk suppression matrix (8 pivots per wave) ----
        unsigned long long pm = 0ull;
        #pragma unroll
        for (int u = 0; u < 8; ++u) {
            const int i = (grp << 3) + u;
            float4 pb = chunkbox[i];          // uniform per iteration -> broadcast
            float pa = (pb.z - pb.x) * (pb.w - pb.y);
            SUPP(pb, pa, mb, marea, s)
            if (s) pm |= (1ull << i);
        }
        part[grp][lane] = pm;
        __syncthreads();                      // (B) chunk_alive + partials final

        // ---- phase R: wave-0 bitmask resolution ----
        if (grp == 0) {
            unsigned long long col = part[0][lane] | part[1][lane] | part[2][lane] | part[3][lane]
                                   | part[4][lane] | part[5][lane] | part[6][lane] | part[7][lane];
            supcol[lane] = col;               // same-wave write->read: LDS ops in order
            const unsigned long long extm = chunk_alive;
            unsigned long long aliveset = 0ull;
            int kc = K;
            #pragma unroll 8
            for (int i = 0; i < 64; ++i) {
                unsigned long long mi = supcol[i];   // uniform loads hoist out of chain
                bool keep = (((extm >> i) & 1ull) != 0ull) &&
                            ((mi & aliveset) == 0ull) && (kc < POST_N);
                if (keep) {                   // wave-uniform branch
                    if (lane == i) {
                        kept[kc] = mb;
                        kept_area[kc] = marea;
                        kept_idx[kc] = base + i;
                    }
                    aliveset |= (1ull << i);
                    ++kc;
                }
            }
            if (lane == 0) kept_cnt = kc;
        }
        __syncthreads();                      // (C) kept list + count visible
        if (kept_cnt >= POST_N) break;        // uniform
    }

    // ---- write outputs (rest of the pre-zeroed buffer stays zero) ----
    const int kc = kept_cnt;
    for (int r = tid; r < kc; r += NMS_BLOCK) {
        float4 bx = kept[r];
        float* ob = out_boxes + ((size_t)img * POST_N + r) * 4;
        ob[0] = bx.x; ob[1] = bx.y; ob[2] = bx.z; ob[3] = bx.w;
        out_scores[(size_t)img * POST_N + r] =
            pre_scores[(size_t)img * PRE_N + kept_idx[r]];
    }
}

extern "C" void kernel_launch(void* const* d_in, const int* in_sizes, int n_in,
                              void* d_out, int out_size, void* d_ws, size_t ws_size,
                              hipStream_t stream) {
    const float* deltas  = (const float*)d_in[0];  // (B, A, 4)
    const float* labels  = (const float*)d_in[1];  // (B, FH, FW, 9)
    const float* anchors = (const float*)d_in[2];  // (A, 4)
    float* out = (float*)d_out;

    const int A = in_sizes[2] / 4;                 // 147456
    const int B = in_sizes[0] / (A * 4);           // 32
    const int ngroups = in_sizes[1] / KCLS;        // B*FH*FW
    const int gpi = ngroups / B;                   // 16384

    // workspace layout
    float* scores     = (float*)d_ws;                                // B*A
    float* pre_boxes  = scores + (size_t)B * A;                      // B*6000*4
    float* pre_scores = pre_boxes + (size_t)B * PRE_N * 4;           // B*6000
    unsigned int* hist  = (unsigned int*)(pre_scores + (size_t)B * PRE_N);  // 2*B*2048
    unsigned int* state = hist + (size_t)2 * B * 2048;               // B*2
    unsigned long long* pool = (unsigned long long*)(state + (size_t)B * 2); // B*NSEG*SEG_CAP u64
    unsigned int* counts = (unsigned int*)(pool + (size_t)B * NSEG * SEG_CAP); // B*NSEG

    float* out_boxes  = out;                        // B*300*4
    float* out_scores = out + (size_t)B * POST_N * 4;

    hipMemsetAsync(d_out, 0, (size_t)out_size * sizeof(float), stream);
    hipMemsetAsync(hist, 0, ((size_t)2 * B * 2048 + 2 * B) * sizeof(unsigned int), stream);

    // pass 1 (bits [31:21]) fused into softmax (plain version, no in-kernel pick)
    softmax_hist_kernel<<<ngroups / 256, 256, 0, stream>>>(
        labels, scores, hist + (size_t)0 * B * 2048, gpi);
    pick_kernel<<<B, PICK_BLOCK, 0, stream>>>(hist + (size_t)0 * B * 2048, state, 21, 2048, 1);

    dim3 hgrid(CHUNKS_PER_IMG, B);
    // pass 2: bits [20:10] -> T = exact top-22-bit prefix of the 6000th score
    hist_kernel<<<hgrid, HIST_BLOCK, 0, stream>>>(
        scores, hist + (size_t)1 * B * 2048, state, A, 10, 2048, 0xFFE00000u);
    pick_kernel<<<B, PICK_BLOCK, 0, stream>>>(hist + (size_t)1 * B * 2048, state, 10, 2048, 0);

    dim3 sgrid(NSEG, B);
    compact_sort_kernel<<<sgrid, 512, 0, stream>>>(scores, state, pool, counts, A);
    rank_decode_kernel<<<sgrid, 256, 0, stream>>>(pool, counts, deltas, anchors,
                                                  pre_boxes, pre_scores, A);

    nms_kernel<<<B, NMS_BLOCK, 0, stream>>>(pre_boxes, pre_scores, out_boxes, out_scores);
}